// Round 17
// baseline (1300.215 us; speedup 1.0000x reference)
//
#include <hip/hip_runtime.h>
#include <hip/hip_bf16.h>

#define B_ 4
#define L_ 4096
#define C_ 2048
#define NH_ 32
#define K_ 16
#define F_ 64
#define NC_ 256
#define EPS_ 1e-6f

typedef _Float16 half8 __attribute__((ext_vector_type(8)));
typedef _Float16 half4 __attribute__((ext_vector_type(4)));
typedef float f32x4 __attribute__((ext_vector_type(4)));

__device__ __forceinline__ float red16(float v) {
  int x;
  x = __builtin_amdgcn_update_dpp(0, __builtin_bit_cast(int, v), 0xB1, 0xF, 0xF, true);
  v += __builtin_bit_cast(float, x);
  x = __builtin_amdgcn_update_dpp(0, __builtin_bit_cast(int, v), 0x4E, 0xF, 0xF, true);
  v += __builtin_bit_cast(float, x);
  x = __builtin_amdgcn_update_dpp(0, __builtin_bit_cast(int, v), 0x124, 0xF, 0xF, true);
  v += __builtin_bit_cast(float, x);
  x = __builtin_amdgcn_update_dpp(0, __builtin_bit_cast(int, v), 0x128, 0xF, 0xF, true);
  v += __builtin_bit_cast(float, x);
  return v;
}

__device__ __forceinline__ void gl_lds16(const _Float16* g, _Float16* l) {
  __builtin_amdgcn_global_load_lds(
      (const __attribute__((address_space(1))) void*)g,
      (__attribute__((address_space(3))) void*)l, 16, 0, 0);
}

// ---------------- cast fp32 -> f16, 8 elems/thread ----------------
__global__ __launch_bounds__(256) void cast_f16(const float* __restrict__ in,
                                                _Float16* __restrict__ out, int n8) {
  int i = blockIdx.x * 256 + threadIdx.x;
  if (i >= n8) return;
  const float4* ip = (const float4*)in;
  float4 a = ip[2*i], b = ip[2*i+1];
  half8 o;
  o[0]=(_Float16)a.x; o[1]=(_Float16)a.y; o[2]=(_Float16)a.z; o[3]=(_Float16)a.w;
  o[4]=(_Float16)b.x; o[5]=(_Float16)b.y; o[6]=(_Float16)b.z; o[7]=(_Float16)b.w;
  ((half8*)out)[i] = o;
}

// ---------------- f16 MFMA GEMM v3: 256x256, BK=64, 8 waves (2x4),
// 2-deep LDS double-buffer, 4-phase quadrant schedule, counted vmcnt
// BEFORE barrier. 4 output regions: reg=bn>>3 -> {C0,C1,C2,C3};
// C0..C2 row-stride 2048, C3 (ilr scores) row-stride 256. ----------
#define BM3 256
#define BN3 256
#define BK3 64

template<typename OT>
__global__ __launch_bounds__(512, 2) void gemm_f16_v3(
    const _Float16* __restrict__ A, const _Float16* __restrict__ Bm,
    OT* __restrict__ C0, OT* __restrict__ C1, OT* __restrict__ C2,
    OT* __restrict__ C3, int Kd)
{
  __shared__ __align__(16) _Float16 As[2][2][128*64];
  __shared__ __align__(16) _Float16 Bs[2][2][128*64];
  const int t = threadIdx.x;
  const int lane = t & 63;
  const int w = t >> 6;
  const int wr = w >> 2, wc = w & 3;
  const int bn = blockIdx.x, bm = blockIdx.y;
  const int ln = lane & 15, q = lane >> 4;

  const int srow = t >> 3, sc = t & 7;
  const int clg = sc ^ (2 * ((srow >> 2) & 1));

  auto stageA = [&](int kt, int h, int db) {
    const _Float16* g = A + ((long)(bm*BM3 + h*128 + srow))*Kd + (long)kt*BK3 + clg*8;
    gl_lds16(g,          &As[db][h][(size_t)srow*64 + sc*8]);
    gl_lds16(g + 64*Kd,  &As[db][h][(size_t)(64+srow)*64 + sc*8]);
  };
  auto stageB = [&](int kt, int h, int db) {
    const _Float16* g = Bm + ((long)(bn*BN3 + h*128 + srow))*Kd + (long)kt*BK3 + clg*8;
    gl_lds16(g,          &Bs[db][h][(size_t)srow*64 + sc*8]);
    gl_lds16(g + 64*Kd,  &Bs[db][h][(size_t)(64+srow)*64 + sc*8]);
  };

  f32x4 acc[8][4];
#pragma unroll
  for (int i = 0; i < 8; ++i)
#pragma unroll
    for (int j = 0; j < 4; ++j) acc[i][j] = (f32x4){0.f,0.f,0.f,0.f};

  half8 af[8][2], bf[4][2];

  stageA(0, 0, 0); stageA(0, 1, 0); stageB(0, 0, 0); stageB(0, 1, 0);

  const int NT = Kd / BK3;
  for (int kt = 0; kt < NT; ++kt) {
    const int db = kt & 1;
    const bool more = (kt + 1 < NT);
    if (more) { stageA(kt+1, 0, db^1); stageB(kt+1, 0, db^1); }
    __builtin_amdgcn_sched_barrier(0);
    if (more) asm volatile("s_waitcnt vmcnt(4)" ::: "memory");
    else      asm volatile("s_waitcnt vmcnt(0)" ::: "memory");
    __builtin_amdgcn_sched_barrier(0);
    __builtin_amdgcn_s_barrier();
    __builtin_amdgcn_sched_barrier(0);

    const _Float16* ap = &As[db][wr][0];
    const _Float16* bp = &Bs[db][wc >> 1][0];
    const int lcb = (wc & 1) * 64;

#pragma unroll
    for (int mi = 0; mi < 4; ++mi)
#pragma unroll
      for (int ks = 0; ks < 2; ++ks) {
        int lr = mi*16 + ln;
        int cp = (ks*4 + q) ^ (2*((lr>>2)&1));
        af[mi][ks] = *(const half8*)(ap + (size_t)lr*64 + cp*8);
      }
#pragma unroll
    for (int ni = 0; ni < 2; ++ni)
#pragma unroll
      for (int ks = 0; ks < 2; ++ks) {
        int lc = lcb + ni*16 + ln;
        int cp = (ks*4 + q) ^ (2*((lc>>2)&1));
        bf[ni][ks] = *(const half8*)(bp + (size_t)lc*64 + cp*8);
      }
    __builtin_amdgcn_s_setprio(1);
#pragma unroll
    for (int mi = 0; mi < 4; ++mi)
#pragma unroll
      for (int ni = 0; ni < 2; ++ni)
#pragma unroll
        for (int ks = 0; ks < 2; ++ks)
          acc[mi][ni] = __builtin_amdgcn_mfma_f32_16x16x32_f16(af[mi][ks], bf[ni][ks], acc[mi][ni], 0, 0, 0);
    __builtin_amdgcn_s_setprio(0);
    if (more) stageA(kt+1, 1, db^1);

#pragma unroll
    for (int mi = 4; mi < 8; ++mi)
#pragma unroll
      for (int ks = 0; ks < 2; ++ks) {
        int lr = mi*16 + ln;
        int cp = (ks*4 + q) ^ (2*((lr>>2)&1));
        af[mi][ks] = *(const half8*)(ap + (size_t)lr*64 + cp*8);
      }
    __builtin_amdgcn_s_setprio(1);
#pragma unroll
    for (int mi = 4; mi < 8; ++mi)
#pragma unroll
      for (int ni = 0; ni < 2; ++ni)
#pragma unroll
        for (int ks = 0; ks < 2; ++ks)
          acc[mi][ni] = __builtin_amdgcn_mfma_f32_16x16x32_f16(af[mi][ks], bf[ni][ks], acc[mi][ni], 0, 0, 0);
    __builtin_amdgcn_s_setprio(0);
    if (more) stageB(kt+1, 1, db^1);

#pragma unroll
    for (int ni = 2; ni < 4; ++ni)
#pragma unroll
      for (int ks = 0; ks < 2; ++ks) {
        int lc = lcb + ni*16 + ln;
        int cp = (ks*4 + q) ^ (2*((lc>>2)&1));
        bf[ni][ks] = *(const half8*)(bp + (size_t)lc*64 + cp*8);
      }
    __builtin_amdgcn_s_setprio(1);
#pragma unroll
    for (int mi = 4; mi < 8; ++mi)
#pragma unroll
      for (int ni = 2; ni < 4; ++ni)
#pragma unroll
        for (int ks = 0; ks < 2; ++ks)
          acc[mi][ni] = __builtin_amdgcn_mfma_f32_16x16x32_f16(af[mi][ks], bf[ni][ks], acc[mi][ni], 0, 0, 0);
    __builtin_amdgcn_s_setprio(0);

    __builtin_amdgcn_s_setprio(1);
#pragma unroll
    for (int mi = 0; mi < 4; ++mi)
#pragma unroll
      for (int ni = 2; ni < 4; ++ni)
#pragma unroll
        for (int ks = 0; ks < 2; ++ks)
          acc[mi][ni] = __builtin_amdgcn_mfma_f32_16x16x32_f16(af[mi][ks], bf[ni][ks], acc[mi][ni], 0, 0, 0);
    __builtin_amdgcn_s_setprio(0);

    __builtin_amdgcn_sched_barrier(0);
    __builtin_amdgcn_s_barrier();
    __builtin_amdgcn_sched_barrier(0);
  }

  const int reg = bn >> 3, bnl = bn & 7;
  OT* C = (reg == 0) ? C0 : ((reg == 1) ? C1 : ((reg == 2) ? C2 : C3));
  const long rstride = (reg == 3) ? 256 : 2048;
  const int cr = q * 4;
#pragma unroll
  for (int mi = 0; mi < 8; ++mi)
#pragma unroll
    for (int ni = 0; ni < 4; ++ni)
#pragma unroll
      for (int r = 0; r < 4; ++r) {
        long row = (long)bm*BM3 + wr*128 + mi*16 + cr + r;
        long col = (long)bnl*256 + wc*64 + ni*16 + ln;
        C[row*rstride + col] = (OT)acc[mi][ni][r];
      }
}

// ---------------- ilr epilogue: coeff from fused-GEMM scores ----------------
__global__ __launch_bounds__(256) void ilr_post(
    const _Float16* __restrict__ s, const float* __restrict__ lin_b,
    float* __restrict__ coeff)
{
  int i = blockIdx.x * 256 + threadIdx.x;       // over B*NH*L = 524288
  int bh = i >> 12, li = i & (L_ - 1);
  int b = bh >> 5, h = bh & 31;
  long row = (long)b * L_ + li;
  float x = (float)s[row * 256 + h] + lin_b[h];
  float sp = (x > 20.f) ? x : log1pf(expf(x));
  int k = li & (K_ - 1);
  coeff[(size_t)bh * L_ + li] = sp * (1.f / (float)(k + 1)) * (1.f / (float)F_);
}

// ---------------- TTT scan v8 (unchanged from R13) ----------
struct Ck2 {
  half4 xbA[4], xsA[4];
  float co4[4], co15;
};

__device__ __forceinline__ void load_ck2(
    Ck2& c, const _Float16* Kp, const _Float16* S, const float* co,
    size_t rowbase, int hoff, size_t cobase, int n, int q, int ln)
{
#pragma unroll
  for (int kt = 0; kt < 4; ++kt) {
    size_t idx = (rowbase + ln) * C_ + hoff + 16*kt + 4*q;
    c.xbA[kt] = *(const half4*)(Kp + idx);
    c.xsA[kt] = *(const half4*)(S  + idx);
  }
#pragma unroll
  for (int r = 0; r < 4; ++r) c.co4[r] = co[cobase + (size_t)n*K_ + 4*q + r];
  c.co15 = co[cobase + (size_t)n*K_ + 15];
}

__global__ __launch_bounds__(128, 1) void scan_kernel(
    const _Float16* __restrict__ Q, const _Float16* __restrict__ Kp,
    const _Float16* __restrict__ V,
    const float* __restrict__ coeff, const float* __restrict__ W1g, const float* __restrict__ b1g,
    const float* __restrict__ ln_w, const float* __restrict__ ln_b,
    _Float16* __restrict__ OF)
{
  const int bh = blockIdx.x;
  const int b = bh >> 5, h = bh & 31;
  const int tid = threadIdx.x;
  const int lane = tid & 63;
  const bool isP = tid < 64;
  const int q = lane >> 4, ln = lane & 15;
  const int hoff = h * F_;
  const size_t cobase = (size_t)bh * L_;
  const size_t brow = (size_t)b * L_;

  __shared__ half4 gzs[4][4][64];

  half4 W1f[4][4];
#pragma unroll
  for (int kt = 0; kt < 4; ++kt)
#pragma unroll
    for (int t = 0; t < 4; ++t) {
      half4 hv;
#pragma unroll
      for (int j = 0; j < 4; ++j)
        hv[j] = (_Float16)W1g[(size_t)h*F_*F_ + (size_t)(16*kt + 4*q + j)*F_ + 16*t + ln];
      W1f[kt][t] = hv;
    }
  float b1r[4], gamt[4], bett[4];
#pragma unroll
  for (int t = 0; t < 4; ++t) {
    b1r[t]  = b1g[hoff + 16*t + ln];
    gamt[t] = ln_w[hoff + 16*t + ln];
    bett[t] = ln_b[hoff + 16*t + ln];
  }
  half4 maskA, maskI;
#pragma unroll
  for (int j = 0; j < 4; ++j) {
    maskA[j] = (_Float16)((4*q + j <= ln) ? 1.f : 0.f);
    maskI[j] = (_Float16)((4*q + j == ln) ? 1.f : 0.f);
  }
  const f32x4 zf4 = (f32x4){0.f, 0.f, 0.f, 0.f};

  const _Float16* S = isP ? V : Q;

  auto iter = [&](int i, Ck2& cur, Ck2& nxt) {
    half4 gzf[4];
    half4 xbTp[4];
    float co15p = 0.f;

    if (isP) {
      if (i < NC_) {
        co15p = cur.co15;
        if (i + 1 < NC_)
          load_ck2(nxt, Kp, S, coeff, brow + (size_t)(i+1)*K_, hoff, cobase, i+1, q, ln);
        f32x4 tgD[4];
#pragma unroll
        for (int t = 0; t < 4; ++t) {
          half4 dd = cur.xsA[t] - cur.xbA[t];
          tgD[t] = __builtin_amdgcn_mfma_f32_16x16x16f16(dd, maskI, zf4, 0, 0, 0);
          f32x4 x = __builtin_amdgcn_mfma_f32_16x16x16f16(cur.xbA[t], maskI, zf4, 0, 0, 0);
          half4 v;
#pragma unroll
          for (int r = 0; r < 4; ++r) v[r] = (_Float16)x[r];
          xbTp[t] = v;
        }
        f32x4 za[4];
#pragma unroll
        for (int t = 0; t < 4; ++t) {
          f32x4 zh = (f32x4){b1r[t], b1r[t], b1r[t], b1r[t]};
#pragma unroll
          for (int kt = 0; kt < 4; ++kt)
            zh = __builtin_amdgcn_mfma_f32_16x16x16f16(cur.xbA[kt], W1f[kt][t], zh, 0, 0, 0);
          za[t] = zh;
        }
#pragma unroll
        for (int r = 0; r < 4; ++r) {
          float zr[4], s1 = 0.f, s2 = 0.f;
#pragma unroll
          for (int t = 0; t < 4; ++t) { zr[t] = za[t][r]; s1 += zr[t]; s2 += zr[t]*zr[t]; }
          s1 = red16(s1); s2 = red16(s2);
          float mu = s1 * (1.f/F_);
          float istd = rsqrtf(s2 * (1.f/F_) - mu*mu + EPS_);
          float xh[4], gy[4], sg = 0.f, sx = 0.f;
#pragma unroll
          for (int t = 0; t < 4; ++t) {
            xh[t] = (zr[t] - mu) * istd;
            gy[t] = (gamt[t]*xh[t] + bett[t] - tgD[t][r]) * gamt[t];
            sg += gy[t]; sx += gy[t]*xh[t];
          }
          sg = red16(sg); sx = red16(sx);
          const float sc = istd * (1.f/F_);
#pragma unroll
          for (int t = 0; t < 4; ++t)
            gzf[t][r] = (_Float16)((F_*gy[t] - sg - xh[t]*sx) * sc);
        }
#pragma unroll
        for (int t = 0; t < 4; ++t) gzs[i & 3][t][lane] = gzf[t];
      }
    } else {
      if (i < NC_)
        load_ck2(nxt, Kp, S, coeff, brow + (size_t)i*K_, hoff, cobase, i, q, ln);
    }

    __syncthreads();

    if (isP) {
      if (i < NC_) {
        f32x4 cum3[4];
#pragma unroll
        for (int t = 0; t < 4; ++t)
          cum3[t] = __builtin_amdgcn_mfma_f32_16x16x16f16(maskA, gzf[t], zf4, 0, 0, 0);
#pragma unroll
        for (int t = 0; t < 4; ++t) {
          float tmp = b1r[t] - co15p * cum3[t][3];
          b1r[t] = __shfl(tmp, 48 + ln, 64);
        }
#pragma unroll
        for (int mt = 0; mt < 4; ++mt)
#pragma unroll
          for (int t = 0; t < 4; ++t) {
            f32x4 d = __builtin_amdgcn_mfma_f32_16x16x16f16(xbTp[mt], gzf[t], zf4, 0, 0, 0);
            half4 dt;
#pragma unroll
            for (int r = 0; r < 4; ++r) dt[r] = (_Float16)(co15p * d[r]);
            W1f[mt][t] = W1f[mt][t] - dt;
          }
      }
    } else {
      if (i > 0) {
        const int jc = i - 1;
        const size_t rowbase = brow + (size_t)jc * K_;
        half4 gz[4];
#pragma unroll
        for (int t = 0; t < 4; ++t) gz[t] = gzs[jc & 3][t][lane];
        f32x4 xcsD[4]; half4 xbT[4];
#pragma unroll
        for (int t = 0; t < 4; ++t) {
          xcsD[t] = __builtin_amdgcn_mfma_f32_16x16x16f16(cur.xsA[t], maskI, zf4, 0, 0, 0);
          f32x4 x = __builtin_amdgcn_mfma_f32_16x16x16f16(cur.xbA[t], maskI, zf4, 0, 0, 0);
          half4 v;
#pragma unroll
          for (int r = 0; r < 4; ++r) v[r] = (_Float16)x[r];
          xbT[t] = v;
        }
        f32x4 at0 = zf4, at1 = zf4;
        at0 = __builtin_amdgcn_mfma_f32_16x16x16f16(cur.xbA[0], cur.xsA[0], at0, 0, 0, 0);
        at0 = __builtin_amdgcn_mfma_f32_16x16x16f16(cur.xbA[1], cur.xsA[1], at0, 0, 0, 0);
        at1 = __builtin_amdgcn_mfma_f32_16x16x16f16(cur.xbA[2], cur.xsA[2], at1, 0, 0, 0);
        at1 = __builtin_amdgcn_mfma_f32_16x16x16f16(cur.xbA[3], cur.xsA[3], at1, 0, 0, 0);
        f32x4 at = at0 + at1;
        half4 atf;
#pragma unroll
        for (int r = 0; r < 4; ++r) atf[r] = (_Float16)((4*q + r <= ln) ? at[r] : 0.f);
        f32x4 cum[4], ag[4];
#pragma unroll
        for (int t = 0; t < 4; ++t) {
          cum[t] = __builtin_amdgcn_mfma_f32_16x16x16f16(maskA, gz[t], zf4, 0, 0, 0);
          ag[t]  = __builtin_amdgcn_mfma_f32_16x16x16f16(atf,   gz[t], zf4, 0, 0, 0);
        }
        float zbf[4][4];
#pragma unroll
        for (int t = 0; t < 4; ++t) {
          f32x4 zh = zf4;
#pragma unroll
          for (int kt = 0; kt < 4; ++kt)
            zh = __builtin_amdgcn_mfma_f32_16x16x16f16(cur.xsA[kt], W1f[kt][t], zh, 0, 0, 0);
#pragma unroll
          for (int r = 0; r < 4; ++r)
            zbf[t][r] = zh[r] + b1r[t] - cur.co4[r]*(ag[t][r] + cum[t][r]);
        }
#pragma unroll
        for (int r = 0; r < 4; ++r) {
          float zr[4], s1 = 0.f, s2 = 0.f;
#pragma unroll
          for (int t = 0; t < 4; ++t) { zr[t] = zbf[t][r]; s1 += zr[t]; s2 += zr[t]*zr[t]; }
          s1 = red16(s1); s2 = red16(s2);
          float mu = s1 * (1.f/F_);
          float istd = rsqrtf(s2 * (1.f/F_) - mu*mu + EPS_);
#pragma unroll
          for (int t = 0; t < 4; ++t) {
            float ov = xcsD[t][r] + gamt[t]*((zr[t] - mu)*istd) + bett[t];
            OF[(rowbase + 4*q + r) * C_ + hoff + 16*t + ln] = (_Float16)ov;
          }
        }
#pragma unroll
        for (int t = 0; t < 4; ++t) {
          float tmp = b1r[t] - cur.co15 * cum[t][3];
          b1r[t] = __shfl(tmp, 48 + ln, 64);
        }
#pragma unroll
        for (int mt = 0; mt < 4; ++mt)
#pragma unroll
          for (int t = 0; t < 4; ++t) {
            f32x4 d = __builtin_amdgcn_mfma_f32_16x16x16f16(xbT[mt], gz[t], zf4, 0, 0, 0);
            half4 dt;
#pragma unroll
            for (int r = 0; r < 4; ++r) dt[r] = (_Float16)(cur.co15 * d[r]);
            W1f[mt][t] = W1f[mt][t] - dt;
          }
      }
    }
  };

  Ck2 cka, ckb;
  if (isP) load_ck2(cka, Kp, S, coeff, brow, hoff, cobase, 0, q, ln);

  for (int i = 0; i < NC_; i += 2) {
    iter(i,     cka, ckb);
    iter(i + 1, ckb, cka);
  }
  iter(NC_, cka, ckb);
}

extern "C" void kernel_launch(void* const* d_in, const int* in_sizes, int n_in,
                              void* d_out, int out_size, void* d_ws, size_t ws_size,
                              hipStream_t stream)
{
  const float* hid   = (const float*)d_in[0];
  const float* q_w   = (const float*)d_in[1];
  const float* k_w   = (const float*)d_in[2];
  const float* v_w   = (const float*)d_in[3];
  const float* o_w   = (const float*)d_in[4];
  const float* lin_w = (const float*)d_in[5];
  const float* lin_b = (const float*)d_in[6];
  const float* ln_w  = (const float*)d_in[7];
  const float* ln_b  = (const float*)d_in[8];
  const float* W1    = (const float*)d_in[9];
  const float* b1    = (const float*)d_in[10];
  float* out = (float*)d_out;

  const size_t BLC = (size_t)B_ * L_ * C_;
  const size_t CC  = (size_t)C_ * C_;
  const size_t ILRW = 256 * (size_t)C_;          // 256 weight rows (32 used)
  const size_t ILRO = (size_t)B_ * L_ * 256;     // score buffer
  _Float16* HF   = (_Float16*)d_ws;              // hid f16; later scan output
  _Float16* WF3  = HF + BLC;                     // [6400][2048] fused weights
  _Float16* KF   = WF3 + 3*CC + ILRW;
  _Float16* VF   = KF + BLC;
  _Float16* SB   = VF + BLC;                     // ilr scores [B*L][256] f16
  float*    CO   = (float*)(SB + ILRO);          // B*NH*L fp32
  _Float16* QF   = (_Float16*)d_out;             // Q f16 in d_out

  const int M = B_ * L_, Kd = C_;
  dim3 ggQKV((3 * C_ + 256) / BN3, M / BM3);     // 25 x 64
  dim3 ggO(C_ / BN3, M / BM3);                   // 8 x 64
  const int n8h = (int)(BLC / 8);
  const int n8w = (int)(CC / 8);
  const int n8l = (int)(NH_ * C_ / 8);           // lin_w elems / 8

  cast_f16<<<(n8h+255)/256, 256, 0, stream>>>(hid, HF, n8h);
  cast_f16<<<(n8w+255)/256, 256, 0, stream>>>(q_w, WF3,        n8w);
  cast_f16<<<(n8w+255)/256, 256, 0, stream>>>(k_w, WF3 + CC,   n8w);
  cast_f16<<<(n8w+255)/256, 256, 0, stream>>>(v_w, WF3 + 2*CC, n8w);
  cast_f16<<<(n8l+255)/256, 256, 0, stream>>>(lin_w, WF3 + 3*CC, n8l);
  gemm_f16_v3<_Float16><<<ggQKV, 512, 0, stream>>>(HF, WF3, QF, KF, VF, SB, Kd);
  ilr_post<<<(B_*NH_*L_)/256, 256, 0, stream>>>(SB, lin_b, CO);
  scan_kernel<<<B_ * NH_, 128, 0, stream>>>(QF, KF, VF, CO, W1, b1, ln_w, ln_b, HF);
  cast_f16<<<(n8w+255)/256, 256, 0, stream>>>(o_w, WF3, n8w);
  gemm_f16_v3<float><<<ggO, 512, 0, stream>>>(HF, WF3, out, out, out, out, Kd);
}

// Round 18
// 1289.305 us; speedup vs baseline: 1.0085x; 1.0085x over previous
//
#include <hip/hip_runtime.h>
#include <hip/hip_bf16.h>

#define B_ 4
#define L_ 4096
#define C_ 2048
#define NH_ 32
#define K_ 16
#define F_ 64
#define NC_ 256
#define EPS_ 1e-6f

typedef _Float16 half8 __attribute__((ext_vector_type(8)));
typedef _Float16 half4 __attribute__((ext_vector_type(4)));
typedef float f32x4 __attribute__((ext_vector_type(4)));

__device__ __forceinline__ float red16(float v) {
  int x;
  x = __builtin_amdgcn_update_dpp(0, __builtin_bit_cast(int, v), 0xB1, 0xF, 0xF, true);
  v += __builtin_bit_cast(float, x);
  x = __builtin_amdgcn_update_dpp(0, __builtin_bit_cast(int, v), 0x4E, 0xF, 0xF, true);
  v += __builtin_bit_cast(float, x);
  x = __builtin_amdgcn_update_dpp(0, __builtin_bit_cast(int, v), 0x124, 0xF, 0xF, true);
  v += __builtin_bit_cast(float, x);
  x = __builtin_amdgcn_update_dpp(0, __builtin_bit_cast(int, v), 0x128, 0xF, 0xF, true);
  v += __builtin_bit_cast(float, x);
  return v;
}

__device__ __forceinline__ void gl_lds16(const _Float16* g, _Float16* l) {
  __builtin_amdgcn_global_load_lds(
      (const __attribute__((address_space(1))) void*)g,
      (__attribute__((address_space(3))) void*)l, 16, 0, 0);
}

// ---------------- cast fp32 -> f16, 8 elems/thread ----------------
__global__ __launch_bounds__(256) void cast_f16(const float* __restrict__ in,
                                                _Float16* __restrict__ out, int n8) {
  int i = blockIdx.x * 256 + threadIdx.x;
  if (i >= n8) return;
  const float4* ip = (const float4*)in;
  float4 a = ip[2*i], b = ip[2*i+1];
  half8 o;
  o[0]=(_Float16)a.x; o[1]=(_Float16)a.y; o[2]=(_Float16)a.z; o[3]=(_Float16)a.w;
  o[4]=(_Float16)b.x; o[5]=(_Float16)b.y; o[6]=(_Float16)b.z; o[7]=(_Float16)b.w;
  ((half8*)out)[i] = o;
}

// ---------------- f16 MFMA GEMM v3b: 256x256, BK=64, 8 waves (2x4),
// 2-deep LDS double-buffer, 4-phase quadrant schedule, counted vmcnt,
// FULL st_16x32 swizzle: chunk ^= (row & 7) (both sides, involution).
// 4 output regions: reg=bn>>3 -> {C0,C1,C2,C3}; C3 row-stride 256. ----------
#define BM3 256
#define BN3 256
#define BK3 64

template<typename OT>
__global__ __launch_bounds__(512, 2) void gemm_f16_v3(
    const _Float16* __restrict__ A, const _Float16* __restrict__ Bm,
    OT* __restrict__ C0, OT* __restrict__ C1, OT* __restrict__ C2,
    OT* __restrict__ C3, int Kd)
{
  __shared__ __align__(16) _Float16 As[2][2][128*64];
  __shared__ __align__(16) _Float16 Bs[2][2][128*64];
  const int t = threadIdx.x;
  const int lane = t & 63;
  const int w = t >> 6;
  const int wr = w >> 2, wc = w & 3;
  const int bn = blockIdx.x, bm = blockIdx.y;
  const int ln = lane & 15, q = lane >> 4;

  // staging: thread t -> phys slot (srow, sc); logical chunk = sc ^ (srow&7)
  // (same for row 64+srow since 64 % 8 == 0)
  const int srow = t >> 3, sc = t & 7;
  const int clg = sc ^ (srow & 7);

  auto stageA = [&](int kt, int h, int db) {
    const _Float16* g = A + ((long)(bm*BM3 + h*128 + srow))*Kd + (long)kt*BK3 + clg*8;
    gl_lds16(g,          &As[db][h][(size_t)srow*64 + sc*8]);
    gl_lds16(g + 64*Kd,  &As[db][h][(size_t)(64+srow)*64 + sc*8]);
  };
  auto stageB = [&](int kt, int h, int db) {
    const _Float16* g = Bm + ((long)(bn*BN3 + h*128 + srow))*Kd + (long)kt*BK3 + clg*8;
    gl_lds16(g,          &Bs[db][h][(size_t)srow*64 + sc*8]);
    gl_lds16(g + 64*Kd,  &Bs[db][h][(size_t)(64+srow)*64 + sc*8]);
  };

  f32x4 acc[8][4];
#pragma unroll
  for (int i = 0; i < 8; ++i)
#pragma unroll
    for (int j = 0; j < 4; ++j) acc[i][j] = (f32x4){0.f,0.f,0.f,0.f};

  half8 af[8][2], bf[4][2];

  stageA(0, 0, 0); stageA(0, 1, 0); stageB(0, 0, 0); stageB(0, 1, 0);

  const int NT = Kd / BK3;
  for (int kt = 0; kt < NT; ++kt) {
    const int db = kt & 1;
    const bool more = (kt + 1 < NT);
    if (more) { stageA(kt+1, 0, db^1); stageB(kt+1, 0, db^1); }
    __builtin_amdgcn_sched_barrier(0);
    if (more) asm volatile("s_waitcnt vmcnt(4)" ::: "memory");
    else      asm volatile("s_waitcnt vmcnt(0)" ::: "memory");
    __builtin_amdgcn_sched_barrier(0);
    __builtin_amdgcn_s_barrier();
    __builtin_amdgcn_sched_barrier(0);

    const _Float16* ap = &As[db][wr][0];
    const _Float16* bp = &Bs[db][wc >> 1][0];
    const int lcb = (wc & 1) * 64;

#pragma unroll
    for (int mi = 0; mi < 4; ++mi)
#pragma unroll
      for (int ks = 0; ks < 2; ++ks) {
        int lr = mi*16 + ln;
        int cp = (ks*4 + q) ^ (lr & 7);
        af[mi][ks] = *(const half8*)(ap + (size_t)lr*64 + cp*8);
      }
#pragma unroll
    for (int ni = 0; ni < 2; ++ni)
#pragma unroll
      for (int ks = 0; ks < 2; ++ks) {
        int lc = lcb + ni*16 + ln;
        int cp = (ks*4 + q) ^ (lc & 7);
        bf[ni][ks] = *(const half8*)(bp + (size_t)lc*64 + cp*8);
      }
    __builtin_amdgcn_s_setprio(1);
#pragma unroll
    for (int mi = 0; mi < 4; ++mi)
#pragma unroll
      for (int ni = 0; ni < 2; ++ni)
#pragma unroll
        for (int ks = 0; ks < 2; ++ks)
          acc[mi][ni] = __builtin_amdgcn_mfma_f32_16x16x32_f16(af[mi][ks], bf[ni][ks], acc[mi][ni], 0, 0, 0);
    __builtin_amdgcn_s_setprio(0);
    if (more) stageA(kt+1, 1, db^1);

#pragma unroll
    for (int mi = 4; mi < 8; ++mi)
#pragma unroll
      for (int ks = 0; ks < 2; ++ks) {
        int lr = mi*16 + ln;
        int cp = (ks*4 + q) ^ (lr & 7);
        af[mi][ks] = *(const half8*)(ap + (size_t)lr*64 + cp*8);
      }
    __builtin_amdgcn_s_setprio(1);
#pragma unroll
    for (int mi = 4; mi < 8; ++mi)
#pragma unroll
      for (int ni = 0; ni < 2; ++ni)
#pragma unroll
        for (int ks = 0; ks < 2; ++ks)
          acc[mi][ni] = __builtin_amdgcn_mfma_f32_16x16x32_f16(af[mi][ks], bf[ni][ks], acc[mi][ni], 0, 0, 0);
    __builtin_amdgcn_s_setprio(0);
    if (more) stageB(kt+1, 1, db^1);

#pragma unroll
    for (int ni = 2; ni < 4; ++ni)
#pragma unroll
      for (int ks = 0; ks < 2; ++ks) {
        int lc = lcb + ni*16 + ln;
        int cp = (ks*4 + q) ^ (lc & 7);
        bf[ni][ks] = *(const half8*)(bp + (size_t)lc*64 + cp*8);
      }
    __builtin_amdgcn_s_setprio(1);
#pragma unroll
    for (int mi = 4; mi < 8; ++mi)
#pragma unroll
      for (int ni = 2; ni < 4; ++ni)
#pragma unroll
        for (int ks = 0; ks < 2; ++ks)
          acc[mi][ni] = __builtin_amdgcn_mfma_f32_16x16x32_f16(af[mi][ks], bf[ni][ks], acc[mi][ni], 0, 0, 0);
    __builtin_amdgcn_s_setprio(0);

    __builtin_amdgcn_s_setprio(1);
#pragma unroll
    for (int mi = 0; mi < 4; ++mi)
#pragma unroll
      for (int ni = 2; ni < 4; ++ni)
#pragma unroll
        for (int ks = 0; ks < 2; ++ks)
          acc[mi][ni] = __builtin_amdgcn_mfma_f32_16x16x32_f16(af[mi][ks], bf[ni][ks], acc[mi][ni], 0, 0, 0);
    __builtin_amdgcn_s_setprio(0);

    __builtin_amdgcn_sched_barrier(0);
    __builtin_amdgcn_s_barrier();
    __builtin_amdgcn_sched_barrier(0);
  }

  const int reg = bn >> 3, bnl = bn & 7;
  OT* C = (reg == 0) ? C0 : ((reg == 1) ? C1 : ((reg == 2) ? C2 : C3));
  const long rstride = (reg == 3) ? 256 : 2048;
  const int cr = q * 4;
#pragma unroll
  for (int mi = 0; mi < 8; ++mi)
#pragma unroll
    for (int ni = 0; ni < 4; ++ni)
#pragma unroll
      for (int r = 0; r < 4; ++r) {
        long row = (long)bm*BM3 + wr*128 + mi*16 + cr + r;
        long col = (long)bnl*256 + wc*64 + ni*16 + ln;
        C[row*rstride + col] = (OT)acc[mi][ni][r];
      }
}

// ---------------- ilr epilogue: coeff from fused-GEMM scores ----------------
__global__ __launch_bounds__(256) void ilr_post(
    const _Float16* __restrict__ s, const float* __restrict__ lin_b,
    float* __restrict__ coeff)
{
  int i = blockIdx.x * 256 + threadIdx.x;       // over B*NH*L = 524288
  int bh = i >> 12, li = i & (L_ - 1);
  int b = bh >> 5, h = bh & 31;
  long row = (long)b * L_ + li;
  float x = (float)s[row * 256 + h] + lin_b[h];
  float sp = (x > 20.f) ? x : log1pf(expf(x));
  int k = li & (K_ - 1);
  coeff[(size_t)bh * L_ + li] = sp * (1.f / (float)(k + 1)) * (1.f / (float)F_);
}

// ---------------- TTT scan v8 (unchanged from R13) ----------
struct Ck2 {
  half4 xbA[4], xsA[4];
  float co4[4], co15;
};

__device__ __forceinline__ void load_ck2(
    Ck2& c, const _Float16* Kp, const _Float16* S, const float* co,
    size_t rowbase, int hoff, size_t cobase, int n, int q, int ln)
{
#pragma unroll
  for (int kt = 0; kt < 4; ++kt) {
    size_t idx = (rowbase + ln) * C_ + hoff + 16*kt + 4*q;
    c.xbA[kt] = *(const half4*)(Kp + idx);
    c.xsA[kt] = *(const half4*)(S  + idx);
  }
#pragma unroll
  for (int r = 0; r < 4; ++r) c.co4[r] = co[cobase + (size_t)n*K_ + 4*q + r];
  c.co15 = co[cobase + (size_t)n*K_ + 15];
}

__global__ __launch_bounds__(128, 1) void scan_kernel(
    const _Float16* __restrict__ Q, const _Float16* __restrict__ Kp,
    const _Float16* __restrict__ V,
    const float* __restrict__ coeff, const float* __restrict__ W1g, const float* __restrict__ b1g,
    const float* __restrict__ ln_w, const float* __restrict__ ln_b,
    _Float16* __restrict__ OF)
{
  const int bh = blockIdx.x;
  const int b = bh >> 5, h = bh & 31;
  const int tid = threadIdx.x;
  const int lane = tid & 63;
  const bool isP = tid < 64;
  const int q = lane >> 4, ln = lane & 15;
  const int hoff = h * F_;
  const size_t cobase = (size_t)bh * L_;
  const size_t brow = (size_t)b * L_;

  __shared__ half4 gzs[4][4][64];

  half4 W1f[4][4];
#pragma unroll
  for (int kt = 0; kt < 4; ++kt)
#pragma unroll
    for (int t = 0; t < 4; ++t) {
      half4 hv;
#pragma unroll
      for (int j = 0; j < 4; ++j)
        hv[j] = (_Float16)W1g[(size_t)h*F_*F_ + (size_t)(16*kt + 4*q + j)*F_ + 16*t + ln];
      W1f[kt][t] = hv;
    }
  float b1r[4], gamt[4], bett[4];
#pragma unroll
  for (int t = 0; t < 4; ++t) {
    b1r[t]  = b1g[hoff + 16*t + ln];
    gamt[t] = ln_w[hoff + 16*t + ln];
    bett[t] = ln_b[hoff + 16*t + ln];
  }
  half4 maskA, maskI;
#pragma unroll
  for (int j = 0; j < 4; ++j) {
    maskA[j] = (_Float16)((4*q + j <= ln) ? 1.f : 0.f);
    maskI[j] = (_Float16)((4*q + j == ln) ? 1.f : 0.f);
  }
  const f32x4 zf4 = (f32x4){0.f, 0.f, 0.f, 0.f};

  const _Float16* S = isP ? V : Q;

  auto iter = [&](int i, Ck2& cur, Ck2& nxt) {
    half4 gzf[4];
    half4 xbTp[4];
    float co15p = 0.f;

    if (isP) {
      if (i < NC_) {
        co15p = cur.co15;
        if (i + 1 < NC_)
          load_ck2(nxt, Kp, S, coeff, brow + (size_t)(i+1)*K_, hoff, cobase, i+1, q, ln);
        f32x4 tgD[4];
#pragma unroll
        for (int t = 0; t < 4; ++t) {
          half4 dd = cur.xsA[t] - cur.xbA[t];
          tgD[t] = __builtin_amdgcn_mfma_f32_16x16x16f16(dd, maskI, zf4, 0, 0, 0);
          f32x4 x = __builtin_amdgcn_mfma_f32_16x16x16f16(cur.xbA[t], maskI, zf4, 0, 0, 0);
          half4 v;
#pragma unroll
          for (int r = 0; r < 4; ++r) v[r] = (_Float16)x[r];
          xbTp[t] = v;
        }
        f32x4 za[4];
#pragma unroll
        for (int t = 0; t < 4; ++t) {
          f32x4 zh = (f32x4){b1r[t], b1r[t], b1r[t], b1r[t]};
#pragma unroll
          for (int kt = 0; kt < 4; ++kt)
            zh = __builtin_amdgcn_mfma_f32_16x16x16f16(cur.xbA[kt], W1f[kt][t], zh, 0, 0, 0);
          za[t] = zh;
        }
#pragma unroll
        for (int r = 0; r < 4; ++r) {
          float zr[4], s1 = 0.f, s2 = 0.f;
#pragma unroll
          for (int t = 0; t < 4; ++t) { zr[t] = za[t][r]; s1 += zr[t]; s2 += zr[t]*zr[t]; }
          s1 = red16(s1); s2 = red16(s2);
          float mu = s1 * (1.f/F_);
          float istd = rsqrtf(s2 * (1.f/F_) - mu*mu + EPS_);
          float xh[4], gy[4], sg = 0.f, sx = 0.f;
#pragma unroll
          for (int t = 0; t < 4; ++t) {
            xh[t] = (zr[t] - mu) * istd;
            gy[t] = (gamt[t]*xh[t] + bett[t] - tgD[t][r]) * gamt[t];
            sg += gy[t]; sx += gy[t]*xh[t];
          }
          sg = red16(sg); sx = red16(sx);
          const float sc = istd * (1.f/F_);
#pragma unroll
          for (int t = 0; t < 4; ++t)
            gzf[t][r] = (_Float16)((F_*gy[t] - sg - xh[t]*sx) * sc);
        }
#pragma unroll
        for (int t = 0; t < 4; ++t) gzs[i & 3][t][lane] = gzf[t];
      }
    } else {
      if (i < NC_)
        load_ck2(nxt, Kp, S, coeff, brow + (size_t)i*K_, hoff, cobase, i, q, ln);
    }

    __syncthreads();

    if (isP) {
      if (i < NC_) {
        f32x4 cum3[4];
#pragma unroll
        for (int t = 0; t < 4; ++t)
          cum3[t] = __builtin_amdgcn_mfma_f32_16x16x16f16(maskA, gzf[t], zf4, 0, 0, 0);
#pragma unroll
        for (int t = 0; t < 4; ++t) {
          float tmp = b1r[t] - co15p * cum3[t][3];
          b1r[t] = __shfl(tmp, 48 + ln, 64);
        }
#pragma unroll
        for (int mt = 0; mt < 4; ++mt)
#pragma unroll
          for (int t = 0; t < 4; ++t) {
            f32x4 d = __builtin_amdgcn_mfma_f32_16x16x16f16(xbTp[mt], gzf[t], zf4, 0, 0, 0);
            half4 dt;
#pragma unroll
            for (int r = 0; r < 4; ++r) dt[r] = (_Float16)(co15p * d[r]);
            W1f[mt][t] = W1f[mt][t] - dt;
          }
      }
    } else {
      if (i > 0) {
        const int jc = i - 1;
        const size_t rowbase = brow + (size_t)jc * K_;
        half4 gz[4];
#pragma unroll
        for (int t = 0; t < 4; ++t) gz[t] = gzs[jc & 3][t][lane];
        f32x4 xcsD[4]; half4 xbT[4];
#pragma unroll
        for (int t = 0; t < 4; ++t) {
          xcsD[t] = __builtin_amdgcn_mfma_f32_16x16x16f16(cur.xsA[t], maskI, zf4, 0, 0, 0);
          f32x4 x = __builtin_amdgcn_mfma_f32_16x16x16f16(cur.xbA[t], maskI, zf4, 0, 0, 0);
          half4 v;
#pragma unroll
          for (int r = 0; r < 4; ++r) v[r] = (_Float16)x[r];
          xbT[t] = v;
        }
        f32x4 at0 = zf4, at1 = zf4;
        at0 = __builtin_amdgcn_mfma_f32_16x16x16f16(cur.xbA[0], cur.xsA[0], at0, 0, 0, 0);
        at0 = __builtin_amdgcn_mfma_f32_16x16x16f16(cur.xbA[1], cur.xsA[1], at0, 0, 0, 0);
        at1 = __builtin_amdgcn_mfma_f32_16x16x16f16(cur.xbA[2], cur.xsA[2], at1, 0, 0, 0);
        at1 = __builtin_amdgcn_mfma_f32_16x16x16f16(cur.xbA[3], cur.xsA[3], at1, 0, 0, 0);
        f32x4 at = at0 + at1;
        half4 atf;
#pragma unroll
        for (int r = 0; r < 4; ++r) atf[r] = (_Float16)((4*q + r <= ln) ? at[r] : 0.f);
        f32x4 cum[4], ag[4];
#pragma unroll
        for (int t = 0; t < 4; ++t) {
          cum[t] = __builtin_amdgcn_mfma_f32_16x16x16f16(maskA, gz[t], zf4, 0, 0, 0);
          ag[t]  = __builtin_amdgcn_mfma_f32_16x16x16f16(atf,   gz[t], zf4, 0, 0, 0);
        }
        float zbf[4][4];
#pragma unroll
        for (int t = 0; t < 4; ++t) {
          f32x4 zh = zf4;
#pragma unroll
          for (int kt = 0; kt < 4; ++kt)
            zh = __builtin_amdgcn_mfma_f32_16x16x16f16(cur.xsA[kt], W1f[kt][t], zh, 0, 0, 0);
#pragma unroll
          for (int r = 0; r < 4; ++r)
            zbf[t][r] = zh[r] + b1r[t] - cur.co4[r]*(ag[t][r] + cum[t][r]);
        }
#pragma unroll
        for (int r = 0; r < 4; ++r) {
          float zr[4], s1 = 0.f, s2 = 0.f;
#pragma unroll
          for (int t = 0; t < 4; ++t) { zr[t] = zbf[t][r]; s1 += zr[t]; s2 += zr[t]*zr[t]; }
          s1 = red16(s1); s2 = red16(s2);
          float mu = s1 * (1.f/F_);
          float istd = rsqrtf(s2 * (1.f/F_) - mu*mu + EPS_);
#pragma unroll
          for (int t = 0; t < 4; ++t) {
            float ov = xcsD[t][r] + gamt[t]*((zr[t] - mu)*istd) + bett[t];
            OF[(rowbase + 4*q + r) * C_ + hoff + 16*t + ln] = (_Float16)ov;
          }
        }
#pragma unroll
        for (int t = 0; t < 4; ++t) {
          float tmp = b1r[t] - cur.co15 * cum[t][3];
          b1r[t] = __shfl(tmp, 48 + ln, 64);
        }
#pragma unroll
        for (int mt = 0; mt < 4; ++mt)
#pragma unroll
          for (int t = 0; t < 4; ++t) {
            f32x4 d = __builtin_amdgcn_mfma_f32_16x16x16f16(xbT[mt], gz[t], zf4, 0, 0, 0);
            half4 dt;
#pragma unroll
            for (int r = 0; r < 4; ++r) dt[r] = (_Float16)(cur.co15 * d[r]);
            W1f[mt][t] = W1f[mt][t] - dt;
          }
      }
    }
  };

  Ck2 cka, ckb;
  if (isP) load_ck2(cka, Kp, S, coeff, brow, hoff, cobase, 0, q, ln);

  for (int i = 0; i < NC_; i += 2) {
    iter(i,     cka, ckb);
    iter(i + 1, ckb, cka);
  }
  iter(NC_, cka, ckb);
}

extern "C" void kernel_launch(void* const* d_in, const int* in_sizes, int n_in,
                              void* d_out, int out_size, void* d_ws, size_t ws_size,
                              hipStream_t stream)
{
  const float* hid   = (const float*)d_in[0];
  const float* q_w   = (const float*)d_in[1];
  const float* k_w   = (const float*)d_in[2];
  const float* v_w   = (const float*)d_in[3];
  const float* o_w   = (const float*)d_in[4];
  const float* lin_w = (const float*)d_in[5];
  const float* lin_b = (const float*)d_in[6];
  const float* ln_w  = (const float*)d_in[7];
  const float* ln_b  = (const float*)d_in[8];
  const float* W1    = (const float*)d_in[9];
  const float* b1    = (const float*)d_in[10];
  float* out = (float*)d_out;

  const size_t BLC = (size_t)B_ * L_ * C_;
  const size_t CC  = (size_t)C_ * C_;
  const size_t ILRW = 256 * (size_t)C_;
  const size_t ILRO = (size_t)B_ * L_ * 256;
  _Float16* HF   = (_Float16*)d_ws;
  _Float16* WF3  = HF + BLC;
  _Float16* KF   = WF3 + 3*CC + ILRW;
  _Float16* VF   = KF + BLC;
  _Float16* SB   = VF + BLC;
  float*    CO   = (float*)(SB + ILRO);
  _Float16* QF   = (_Float16*)d_out;

  const int M = B_ * L_, Kd = C_;
  dim3 ggQKV((3 * C_ + 256) / BN3, M / BM3);
  dim3 ggO(C_ / BN3, M / BM3);
  const int n8h = (int)(BLC / 8);
  const int n8w = (int)(CC / 8);
  const int n8l = (int)(NH_ * C_ / 8);

  cast_f16<<<(n8h+255)/256, 256, 0, stream>>>(hid, HF, n8h);
  cast_f16<<<(n8w+255)/256, 256, 0, stream>>>(q_w, WF3,        n8w);
  cast_f16<<<(n8w+255)/256, 256, 0, stream>>>(k_w, WF3 + CC,   n8w);
  cast_f16<<<(n8w+255)/256, 256, 0, stream>>>(v_w, WF3 + 2*CC, n8w);
  cast_f16<<<(n8l+255)/256, 256, 0, stream>>>(lin_w, WF3 + 3*CC, n8l);
  gemm_f16_v3<_Float16><<<ggQKV, 512, 0, stream>>>(HF, WF3, QF, KF, VF, SB, Kd);
  ilr_post<<<(B_*NH_*L_)/256, 256, 0, stream>>>(SB, lin_b, CO);
  scan_kernel<<<B_ * NH_, 128, 0, stream>>>(QF, KF, VF, CO, W1, b1, ln_w, ln_b, HF);
  cast_f16<<<(n8w+255)/256, 256, 0, stream>>>(o_w, WF3, n8w);
  gemm_f16_v3<float><<<ggO, 512, 0, stream>>>(HF, WF3, out, out, out, out, Kd);
}

// Round 20
// 1260.934 us; speedup vs baseline: 1.0312x; 1.0225x over previous
//
#include <hip/hip_runtime.h>
#include <hip/hip_bf16.h>

#define B_ 4
#define L_ 4096
#define C_ 2048
#define NH_ 32
#define K_ 16
#define F_ 64
#define NC_ 256
#define EPS_ 1e-6f

typedef _Float16 half8 __attribute__((ext_vector_type(8)));
typedef _Float16 half4 __attribute__((ext_vector_type(4)));
typedef float f32x4 __attribute__((ext_vector_type(4)));

__device__ __forceinline__ float red16(float v) {
  int x;
  x = __builtin_amdgcn_update_dpp(0, __builtin_bit_cast(int, v), 0xB1, 0xF, 0xF, true);
  v += __builtin_bit_cast(float, x);
  x = __builtin_amdgcn_update_dpp(0, __builtin_bit_cast(int, v), 0x4E, 0xF, 0xF, true);
  v += __builtin_bit_cast(float, x);
  x = __builtin_amdgcn_update_dpp(0, __builtin_bit_cast(int, v), 0x124, 0xF, 0xF, true);
  v += __builtin_bit_cast(float, x);
  x = __builtin_amdgcn_update_dpp(0, __builtin_bit_cast(int, v), 0x128, 0xF, 0xF, true);
  v += __builtin_bit_cast(float, x);
  return v;
}

__device__ __forceinline__ void gl_lds16(const _Float16* g, _Float16* l) {
  __builtin_amdgcn_global_load_lds(
      (const __attribute__((address_space(1))) void*)g,
      (__attribute__((address_space(3))) void*)l, 16, 0, 0);
}

// ---------------- cast fp32 -> f16, 8 elems/thread ----------------
__global__ __launch_bounds__(256) void cast_f16(const float* __restrict__ in,
                                                _Float16* __restrict__ out, int n8) {
  int i = blockIdx.x * 256 + threadIdx.x;
  if (i >= n8) return;
  const float4* ip = (const float4*)in;
  float4 a = ip[2*i], b = ip[2*i+1];
  half8 o;
  o[0]=(_Float16)a.x; o[1]=(_Float16)a.y; o[2]=(_Float16)a.z; o[3]=(_Float16)a.w;
  o[4]=(_Float16)b.x; o[5]=(_Float16)b.y; o[6]=(_Float16)b.z; o[7]=(_Float16)b.w;
  ((half8*)out)[i] = o;
}

// ---------------- f16 MFMA GEMM (R18 coarse schedule, known-good) +
// T1 XCD-chunked block swizzle (bijective; bm-major decode so each XCD
// owns a contiguous bm range -> A panels fetched once per XCD chunk).
// st_16x32 swizzle (chunk ^= row&7) both sides; 0 bank conflicts (R18). ----
#define BM3 256
#define BN3 256
#define BK3 64

template<typename OT>
__global__ __launch_bounds__(512, 2) void gemm_f16_v3(
    const _Float16* __restrict__ A, const _Float16* __restrict__ Bm,
    OT* __restrict__ C0, OT* __restrict__ C1, OT* __restrict__ C2,
    OT* __restrict__ C3, int Kd)
{
  __shared__ __align__(16) _Float16 As[2][2][128*64];
  __shared__ __align__(16) _Float16 Bs[2][2][128*64];
  const int t = threadIdx.x;
  const int lane = t & 63;
  const int w = t >> 6;
  const int wr = w >> 2, wc = w & 3;
  // XCD-chunked swizzle: orig id round-robins XCDs; remap so XCD i gets a
  // contiguous chunk; decode bm-major -> XCD i owns bm in [i*chunk/Nx, ...)
  const int nwg = gridDim.x * gridDim.y;
  const int orig = blockIdx.y * gridDim.x + blockIdx.x;
  const int nl = (orig & 7) * (nwg >> 3) + (orig >> 3);
  const int bm = nl / gridDim.x;
  const int bn = nl % gridDim.x;
  const int ln = lane & 15, q = lane >> 4;

  const int srow = t >> 3, sc = t & 7;
  const int clg = sc ^ (srow & 7);

  auto stageA = [&](int kt, int h, int db) {
    const _Float16* g = A + ((long)(bm*BM3 + h*128 + srow))*Kd + (long)kt*BK3 + clg*8;
    gl_lds16(g,          &As[db][h][(size_t)srow*64 + sc*8]);
    gl_lds16(g + 64*Kd,  &As[db][h][(size_t)(64+srow)*64 + sc*8]);
  };
  auto stageB = [&](int kt, int h, int db) {
    const _Float16* g = Bm + ((long)(bn*BN3 + h*128 + srow))*Kd + (long)kt*BK3 + clg*8;
    gl_lds16(g,          &Bs[db][h][(size_t)srow*64 + sc*8]);
    gl_lds16(g + 64*Kd,  &Bs[db][h][(size_t)(64+srow)*64 + sc*8]);
  };

  f32x4 acc[8][4];
#pragma unroll
  for (int i = 0; i < 8; ++i)
#pragma unroll
    for (int j = 0; j < 4; ++j) acc[i][j] = (f32x4){0.f,0.f,0.f,0.f};

  half8 af[8][2], bf[4][2];

  stageA(0, 0, 0); stageA(0, 1, 0); stageB(0, 0, 0); stageB(0, 1, 0);

  const int NT = Kd / BK3;
  for (int kt = 0; kt < NT; ++kt) {
    const int db = kt & 1;
    const bool more = (kt + 1 < NT);
    if (more) { stageA(kt+1, 0, db^1); stageB(kt+1, 0, db^1); }
    __builtin_amdgcn_sched_barrier(0);
    if (more) asm volatile("s_waitcnt vmcnt(4)" ::: "memory");
    else      asm volatile("s_waitcnt vmcnt(0)" ::: "memory");
    __builtin_amdgcn_sched_barrier(0);
    __builtin_amdgcn_s_barrier();
    __builtin_amdgcn_sched_barrier(0);

    const _Float16* ap = &As[db][wr][0];
    const _Float16* bp = &Bs[db][wc >> 1][0];
    const int lcb = (wc & 1) * 64;

#pragma unroll
    for (int mi = 0; mi < 4; ++mi)
#pragma unroll
      for (int ks = 0; ks < 2; ++ks) {
        int lr = mi*16 + ln;
        int cp = (ks*4 + q) ^ (lr & 7);
        af[mi][ks] = *(const half8*)(ap + (size_t)lr*64 + cp*8);
      }
#pragma unroll
    for (int ni = 0; ni < 2; ++ni)
#pragma unroll
      for (int ks = 0; ks < 2; ++ks) {
        int lc = lcb + ni*16 + ln;
        int cp = (ks*4 + q) ^ (lc & 7);
        bf[ni][ks] = *(const half8*)(bp + (size_t)lc*64 + cp*8);
      }
    __builtin_amdgcn_s_setprio(1);
#pragma unroll
    for (int mi = 0; mi < 4; ++mi)
#pragma unroll
      for (int ni = 0; ni < 2; ++ni)
#pragma unroll
        for (int ks = 0; ks < 2; ++ks)
          acc[mi][ni] = __builtin_amdgcn_mfma_f32_16x16x32_f16(af[mi][ks], bf[ni][ks], acc[mi][ni], 0, 0, 0);
    __builtin_amdgcn_s_setprio(0);
    if (more) stageA(kt+1, 1, db^1);

#pragma unroll
    for (int mi = 4; mi < 8; ++mi)
#pragma unroll
      for (int ks = 0; ks < 2; ++ks) {
        int lr = mi*16 + ln;
        int cp = (ks*4 + q) ^ (lr & 7);
        af[mi][ks] = *(const half8*)(ap + (size_t)lr*64 + cp*8);
      }
    __builtin_amdgcn_s_setprio(1);
#pragma unroll
    for (int mi = 4; mi < 8; ++mi)
#pragma unroll
      for (int ni = 0; ni < 2; ++ni)
#pragma unroll
        for (int ks = 0; ks < 2; ++ks)
          acc[mi][ni] = __builtin_amdgcn_mfma_f32_16x16x32_f16(af[mi][ks], bf[ni][ks], acc[mi][ni], 0, 0, 0);
    __builtin_amdgcn_s_setprio(0);
    if (more) stageB(kt+1, 1, db^1);

#pragma unroll
    for (int ni = 2; ni < 4; ++ni)
#pragma unroll
      for (int ks = 0; ks < 2; ++ks) {
        int lc = lcb + ni*16 + ln;
        int cp = (ks*4 + q) ^ (lc & 7);
        bf[ni][ks] = *(const half8*)(bp + (size_t)lc*64 + cp*8);
      }
    __builtin_amdgcn_s_setprio(1);
#pragma unroll
    for (int mi = 4; mi < 8; ++mi)
#pragma unroll
      for (int ni = 2; ni < 4; ++ni)
#pragma unroll
        for (int ks = 0; ks < 2; ++ks)
          acc[mi][ni] = __builtin_amdgcn_mfma_f32_16x16x32_f16(af[mi][ks], bf[ni][ks], acc[mi][ni], 0, 0, 0);
    __builtin_amdgcn_s_setprio(0);

    __builtin_amdgcn_s_setprio(1);
#pragma unroll
    for (int mi = 0; mi < 4; ++mi)
#pragma unroll
      for (int ni = 2; ni < 4; ++ni)
#pragma unroll
        for (int ks = 0; ks < 2; ++ks)
          acc[mi][ni] = __builtin_amdgcn_mfma_f32_16x16x32_f16(af[mi][ks], bf[ni][ks], acc[mi][ni], 0, 0, 0);
    __builtin_amdgcn_s_setprio(0);

    __builtin_amdgcn_sched_barrier(0);
    __builtin_amdgcn_s_barrier();
    __builtin_amdgcn_sched_barrier(0);
  }

  const int reg = bn >> 3, bnl = bn & 7;
  OT* C = (reg == 0) ? C0 : ((reg == 1) ? C1 : ((reg == 2) ? C2 : C3));
  const long rstride = (reg == 3) ? 256 : 2048;
  const int cr = q * 4;
#pragma unroll
  for (int mi = 0; mi < 8; ++mi)
#pragma unroll
    for (int ni = 0; ni < 4; ++ni)
#pragma unroll
      for (int r = 0; r < 4; ++r) {
        long row = (long)bm*BM3 + wr*128 + mi*16 + cr + r;
        long col = (long)bnl*256 + wc*64 + ni*16 + ln;
        C[row*rstride + col] = (OT)acc[mi][ni][r];
      }
}

// ---------------- ilr epilogue: coeff from fused-GEMM scores ----------------
__global__ __launch_bounds__(256) void ilr_post(
    const _Float16* __restrict__ s, const float* __restrict__ lin_b,
    float* __restrict__ coeff)
{
  int i = blockIdx.x * 256 + threadIdx.x;       // over B*NH*L = 524288
  int bh = i >> 12, li = i & (L_ - 1);
  int b = bh >> 5, h = bh & 31;
  long row = (long)b * L_ + li;
  float x = (float)s[row * 256 + h] + lin_b[h];
  float sp = (x > 20.f) ? x : log1pf(expf(x));
  int k = li & (K_ - 1);
  coeff[(size_t)bh * L_ + li] = sp * (1.f / (float)(k + 1)) * (1.f / (float)F_);
}

// ---------------- TTT scan v8 (unchanged from R13) ----------
struct Ck2 {
  half4 xbA[4], xsA[4];
  float co4[4], co15;
};

__device__ __forceinline__ void load_ck2(
    Ck2& c, const _Float16* Kp, const _Float16* S, const float* co,
    size_t rowbase, int hoff, size_t cobase, int n, int q, int ln)
{
#pragma unroll
  for (int kt = 0; kt < 4; ++kt) {
    size_t idx = (rowbase + ln) * C_ + hoff + 16*kt + 4*q;
    c.xbA[kt] = *(const half4*)(Kp + idx);
    c.xsA[kt] = *(const half4*)(S  + idx);
  }
#pragma unroll
  for (int r = 0; r < 4; ++r) c.co4[r] = co[cobase + (size_t)n*K_ + 4*q + r];
  c.co15 = co[cobase + (size_t)n*K_ + 15];
}

__global__ __launch_bounds__(128, 1) void scan_kernel(
    const _Float16* __restrict__ Q, const _Float16* __restrict__ Kp,
    const _Float16* __restrict__ V,
    const float* __restrict__ coeff, const float* __restrict__ W1g, const float* __restrict__ b1g,
    const float* __restrict__ ln_w, const float* __restrict__ ln_b,
    _Float16* __restrict__ OF)
{
  const int bh = blockIdx.x;
  const int b = bh >> 5, h = bh & 31;
  const int tid = threadIdx.x;
  const int lane = tid & 63;
  const bool isP = tid < 64;
  const int q = lane >> 4, ln = lane & 15;
  const int hoff = h * F_;
  const size_t cobase = (size_t)bh * L_;
  const size_t brow = (size_t)b * L_;

  __shared__ half4 gzs[4][4][64];

  half4 W1f[4][4];
#pragma unroll
  for (int kt = 0; kt < 4; ++kt)
#pragma unroll
    for (int t = 0; t < 4; ++t) {
      half4 hv;
#pragma unroll
      for (int j = 0; j < 4; ++j)
        hv[j] = (_Float16)W1g[(size_t)h*F_*F_ + (size_t)(16*kt + 4*q + j)*F_ + 16*t + ln];
      W1f[kt][t] = hv;
    }
  float b1r[4], gamt[4], bett[4];
#pragma unroll
  for (int t = 0; t < 4; ++t) {
    b1r[t]  = b1g[hoff + 16*t + ln];
    gamt[t] = ln_w[hoff + 16*t + ln];
    bett[t] = ln_b[hoff + 16*t + ln];
  }
  half4 maskA, maskI;
#pragma unroll
  for (int j = 0; j < 4; ++j) {
    maskA[j] = (_Float16)((4*q + j <= ln) ? 1.f : 0.f);
    maskI[j] = (_Float16)((4*q + j == ln) ? 1.f : 0.f);
  }
  const f32x4 zf4 = (f32x4){0.f, 0.f, 0.f, 0.f};

  const _Float16* S = isP ? V : Q;

  auto iter = [&](int i, Ck2& cur, Ck2& nxt) {
    half4 gzf[4];
    half4 xbTp[4];
    float co15p = 0.f;

    if (isP) {
      if (i < NC_) {
        co15p = cur.co15;
        if (i + 1 < NC_)
          load_ck2(nxt, Kp, S, coeff, brow + (size_t)(i+1)*K_, hoff, cobase, i+1, q, ln);
        f32x4 tgD[4];
#pragma unroll
        for (int t = 0; t < 4; ++t) {
          half4 dd = cur.xsA[t] - cur.xbA[t];
          tgD[t] = __builtin_amdgcn_mfma_f32_16x16x16f16(dd, maskI, zf4, 0, 0, 0);
          f32x4 x = __builtin_amdgcn_mfma_f32_16x16x16f16(cur.xbA[t], maskI, zf4, 0, 0, 0);
          half4 v;
#pragma unroll
          for (int r = 0; r < 4; ++r) v[r] = (_Float16)x[r];
          xbTp[t] = v;
        }
        f32x4 za[4];
#pragma unroll
        for (int t = 0; t < 4; ++t) {
          f32x4 zh = (f32x4){b1r[t], b1r[t], b1r[t], b1r[t]};
#pragma unroll
          for (int kt = 0; kt < 4; ++kt)
            zh = __builtin_amdgcn_mfma_f32_16x16x16f16(cur.xbA[kt], W1f[kt][t], zh, 0, 0, 0);
          za[t] = zh;
        }
#pragma unroll
        for (int r = 0; r < 4; ++r) {
          float zr[4], s1 = 0.f, s2 = 0.f;
#pragma unroll
          for (int t = 0; t < 4; ++t) { zr[t] = za[t][r]; s1 += zr[t]; s2 += zr[t]*zr[t]; }
          s1 = red16(s1); s2 = red16(s2);
          float mu = s1 * (1.f/F_);
          float istd = rsqrtf(s2 * (1.f/F_) - mu*mu + EPS_);
          float xh[4], gy[4], sg = 0.f, sx = 0.f;
#pragma unroll
          for (int t = 0; t < 4; ++t) {
            xh[t] = (zr[t] - mu) * istd;
            gy[t] = (gamt[t]*xh[t] + bett[t] - tgD[t][r]) * gamt[t];
            sg += gy[t]; sx += gy[t]*xh[t];
          }
          sg = red16(sg); sx = red16(sx);
          const float sc = istd * (1.f/F_);
#pragma unroll
          for (int t = 0; t < 4; ++t)
            gzf[t][r] = (_Float16)((F_*gy[t] - sg - xh[t]*sx) * sc);
        }
#pragma unroll
        for (int t = 0; t < 4; ++t) gzs[i & 3][t][lane] = gzf[t];
      }
    } else {
      if (i < NC_)
        load_ck2(nxt, Kp, S, coeff, brow + (size_t)i*K_, hoff, cobase, i, q, ln);
    }

    __syncthreads();

    if (isP) {
      if (i < NC_) {
        f32x4 cum3[4];
#pragma unroll
        for (int t = 0; t < 4; ++t)
          cum3[t] = __builtin_amdgcn_mfma_f32_16x16x16f16(maskA, gzf[t], zf4, 0, 0, 0);
#pragma unroll
        for (int t = 0; t < 4; ++t) {
          float tmp = b1r[t] - co15p * cum3[t][3];
          b1r[t] = __shfl(tmp, 48 + ln, 64);
        }
#pragma unroll
        for (int mt = 0; mt < 4; ++mt)
#pragma unroll
          for (int t = 0; t < 4; ++t) {
            f32x4 d = __builtin_amdgcn_mfma_f32_16x16x16f16(xbTp[mt], gzf[t], zf4, 0, 0, 0);
            half4 dt;
#pragma unroll
            for (int r = 0; r < 4; ++r) dt[r] = (_Float16)(co15p * d[r]);
            W1f[mt][t] = W1f[mt][t] - dt;
          }
      }
    } else {
      if (i > 0) {
        const int jc = i - 1;
        const size_t rowbase = brow + (size_t)jc * K_;
        half4 gz[4];
#pragma unroll
        for (int t = 0; t < 4; ++t) gz[t] = gzs[jc & 3][t][lane];
        f32x4 xcsD[4]; half4 xbT[4];
#pragma unroll
        for (int t = 0; t < 4; ++t) {
          xcsD[t] = __builtin_amdgcn_mfma_f32_16x16x16f16(cur.xsA[t], maskI, zf4, 0, 0, 0);
          f32x4 x = __builtin_amdgcn_mfma_f32_16x16x16f16(cur.xbA[t], maskI, zf4, 0, 0, 0);
          half4 v;
#pragma unroll
          for (int r = 0; r < 4; ++r) v[r] = (_Float16)x[r];
          xbT[t] = v;
        }
        f32x4 at0 = zf4, at1 = zf4;
        at0 = __builtin_amdgcn_mfma_f32_16x16x16f16(cur.xbA[0], cur.xsA[0], at0, 0, 0, 0);
        at0 = __builtin_amdgcn_mfma_f32_16x16x16f16(cur.xbA[1], cur.xsA[1], at0, 0, 0, 0);
        at1 = __builtin_amdgcn_mfma_f32_16x16x16f16(cur.xbA[2], cur.xsA[2], at1, 0, 0, 0);
        at1 = __builtin_amdgcn_mfma_f32_16x16x16f16(cur.xbA[3], cur.xsA[3], at1, 0, 0, 0);
        f32x4 at = at0 + at1;
        half4 atf;
#pragma unroll
        for (int r = 0; r < 4; ++r) atf[r] = (_Float16)((4*q + r <= ln) ? at[r] : 0.f);
        f32x4 cum[4], ag[4];
#pragma unroll
        for (int t = 0; t < 4; ++t) {
          cum[t] = __builtin_amdgcn_mfma_f32_16x16x16f16(maskA, gz[t], zf4, 0, 0, 0);
          ag[t]  = __builtin_amdgcn_mfma_f32_16x16x16f16(atf,   gz[t], zf4, 0, 0, 0);
        }
        float zbf[4][4];
#pragma unroll
        for (int t = 0; t < 4; ++t) {
          f32x4 zh = zf4;
#pragma unroll
          for (int kt = 0; kt < 4; ++kt)
            zh = __builtin_amdgcn_mfma_f32_16x16x16f16(cur.xsA[kt], W1f[kt][t], zh, 0, 0, 0);
#pragma unroll
          for (int r = 0; r < 4; ++r)
            zbf[t][r] = zh[r] + b1r[t] - cur.co4[r]*(ag[t][r] + cum[t][r]);
        }
#pragma unroll
        for (int r = 0; r < 4; ++r) {
          float zr[4], s1 = 0.f, s2 = 0.f;
#pragma unroll
          for (int t = 0; t < 4; ++t) { zr[t] = zbf[t][r]; s1 += zr[t]; s2 += zr[t]*zr[t]; }
          s1 = red16(s1); s2 = red16(s2);
          float mu = s1 * (1.f/F_);
          float istd = rsqrtf(s2 * (1.f/F_) - mu*mu + EPS_);
#pragma unroll
          for (int t = 0; t < 4; ++t) {
            float ov = xcsD[t][r] + gamt[t]*((zr[t] - mu)*istd) + bett[t];
            OF[(rowbase + 4*q + r) * C_ + hoff + 16*t + ln] = (_Float16)ov;
          }
        }
#pragma unroll
        for (int t = 0; t < 4; ++t) {
          float tmp = b1r[t] - cur.co15 * cum[t][3];
          b1r[t] = __shfl(tmp, 48 + ln, 64);
        }
#pragma unroll
        for (int mt = 0; mt < 4; ++mt)
#pragma unroll
          for (int t = 0; t < 4; ++t) {
            f32x4 d = __builtin_amdgcn_mfma_f32_16x16x16f16(xbT[mt], gz[t], zf4, 0, 0, 0);
            half4 dt;
#pragma unroll
            for (int r = 0; r < 4; ++r) dt[r] = (_Float16)(cur.co15 * d[r]);
            W1f[mt][t] = W1f[mt][t] - dt;
          }
      }
    }
  };

  Ck2 cka, ckb;
  if (isP) load_ck2(cka, Kp, S, coeff, brow, hoff, cobase, 0, q, ln);

  for (int i = 0; i < NC_; i += 2) {
    iter(i,     cka, ckb);
    iter(i + 1, ckb, cka);
  }
  iter(NC_, cka, ckb);
}

extern "C" void kernel_launch(void* const* d_in, const int* in_sizes, int n_in,
                              void* d_out, int out_size, void* d_ws, size_t ws_size,
                              hipStream_t stream)
{
  const float* hid   = (const float*)d_in[0];
  const float* q_w   = (const float*)d_in[1];
  const float* k_w   = (const float*)d_in[2];
  const float* v_w   = (const float*)d_in[3];
  const float* o_w   = (const float*)d_in[4];
  const float* lin_w = (const float*)d_in[5];
  const float* lin_b = (const float*)d_in[6];
  const float* ln_w  = (const float*)d_in[7];
  const float* ln_b  = (const float*)d_in[8];
  const float* W1    = (const float*)d_in[9];
  const float* b1    = (const float*)d_in[10];
  float* out = (float*)d_out;

  const size_t BLC = (size_t)B_ * L_ * C_;
  const size_t CC  = (size_t)C_ * C_;
  const size_t ILRW = 256 * (size_t)C_;
  const size_t ILRO = (size_t)B_ * L_ * 256;
  _Float16* HF   = (_Float16*)d_ws;
  _Float16* WF3  = HF + BLC;
  _Float16* KF   = WF3 + 3*CC + ILRW;
  _Float16* VF   = KF + BLC;
  _Float16* SB   = VF + BLC;
  float*    CO   = (float*)(SB + ILRO);
  _Float16* QF   = (_Float16*)d_out;

  const int M = B_ * L_, Kd = C_;
  dim3 ggQKV((3 * C_ + 256) / BN3, M / BM3);
  dim3 ggO(C_ / BN3, M / BM3);
  const int n8h = (int)(BLC / 8);
  const int n8w = (int)(CC / 8);
  const int n8l = (int)(NH_ * C_ / 8);

  cast_f16<<<(n8h+255)/256, 256, 0, stream>>>(hid, HF, n8h);
  cast_f16<<<(n8w+255)/256, 256, 0, stream>>>(q_w, WF3,        n8w);
  cast_f16<<<(n8w+255)/256, 256, 0, stream>>>(k_w, WF3 + CC,   n8w);
  cast_f16<<<(n8w+255)/256, 256, 0, stream>>>(v_w, WF3 + 2*CC, n8w);
  cast_f16<<<(n8l+255)/256, 256, 0, stream>>>(lin_w, WF3 + 3*CC, n8l);
  gemm_f16_v3<_Float16><<<ggQKV, 512, 0, stream>>>(HF, WF3, QF, KF, VF, SB, Kd);
  ilr_post<<<(B_*NH_*L_)/256, 256, 0, stream>>>(SB, lin_b, CO);
  scan_kernel<<<B_ * NH_, 128, 0, stream>>>(QF, KF, VF, CO, W1, b1, ln_w, ln_b, HF);
  cast_f16<<<(n8w+255)/256, 256, 0, stream>>>(o_w, WF3, n8w);
  gemm_f16_v3<float><<<ggO, 512, 0, stream>>>(HF, WF3, out, out, out, out, Kd);
}